// Round 8
// baseline (47.536 us; speedup 1.0000x reference)
//
#include <hip/hip_runtime.h>
#include <hip/hip_bf16.h>

#define N_ATOMS 2048
#define C_DIM   128
#define C_PAIR  16
#define BLK_K   128
#define LN_EPS  1e-5f

typedef float f32x4 __attribute__((ext_vector_type(4)));
typedef short s16x8 __attribute__((ext_vector_type(8)));

__device__ __forceinline__ float bf_lo(unsigned int p) {
    union { unsigned int i; float f; } u; u.i = p << 16; return u.f;
}
__device__ __forceinline__ float bf_hi(unsigned int p) {
    union { unsigned int i; float f; } u; u.i = p & 0xffff0000u; return u.f;
}
__device__ __forceinline__ float bf2f(unsigned short s) {
    union { unsigned int i; float f; } u; u.i = ((unsigned int)s) << 16; return u.f;
}
__device__ __forceinline__ unsigned short f2bf(float f) {
    union { float f; unsigned int i; } u; u.f = f;
    const unsigned int r = u.i + 0x7fffu + ((u.i >> 16) & 1u);  // RNE
    return (unsigned short)(r >> 16);
}

// A-fragment read from swizzled bf16 LDS tile [16][rowBytes/2].
__device__ __forceinline__ s16x8 lda_frag(const unsigned short* base,
                                          int rowBytes, int kstep, int lane) {
    const int m    = lane & 15;
    const int koff = kstep * 64 + ((lane >> 4) << 4);
    const int addr = m * rowBytes + (koff ^ ((m & 7) << 4));
    return *reinterpret_cast<const s16x8*>(
        reinterpret_cast<const char*>(base) + addr);
}

// ---------------------------------------------------------------------------
// Weight packing: W [Nout][K] f32 row-major -> bf16 B-fragment stream.
// units: Wout 32 (8x4), W1 128 (32x4), W2 128 (8x16)  => 288 total
// ---------------------------------------------------------------------------
__device__ void pack_unit(int u, int lane,
                          const float* __restrict__ Wout,
                          const float* __restrict__ W1,
                          const float* __restrict__ W2,
                          unsigned short* __restrict__ WoutP,
                          unsigned short* __restrict__ W1P,
                          unsigned short* __restrict__ W2P)
{
    const float* W; unsigned short* P; int K, local;
    if (u < 32)       { W = Wout; P = WoutP; K = 128; local = u; }
    else if (u < 160) { W = W1;   P = W1P;   K = 128; local = u - 32; }
    else              { W = W2;   P = W2P;   K = 512; local = u - 160; }
    const int ksteps = K >> 5;
    const int ntile  = local / ksteps;
    const int kstep  = local - ntile * ksteps;
    const int n  = ntile * 16 + (lane & 15);
    const int k0 = kstep * 32 + ((lane >> 4) << 3);
    const float4* src = reinterpret_cast<const float4*>(W + (size_t)n * K + k0);
    const float4 a = src[0], b = src[1];
    s16x8 o;
    o[0] = (short)f2bf(a.x); o[1] = (short)f2bf(a.y);
    o[2] = (short)f2bf(a.z); o[3] = (short)f2bf(a.w);
    o[4] = (short)f2bf(b.x); o[5] = (short)f2bf(b.y);
    o[6] = (short)f2bf(b.z); o[7] = (short)f2bf(b.w);
    reinterpret_cast<s16x8*>(P)[local * 64 + lane] = o;
}

// ---------------------------------------------------------------------------
// K1: LayerNorm(x) -> swizzled bf16 LDS; q/k/v via MFMA, weight B-fragments
// loaded directly from f32 global. 512 threads, 16 rows/block, grid 128.
// ---------------------------------------------------------------------------
__global__ __launch_bounds__(512) void ln_qkv_kernel(
    const float* __restrict__ x,
    const float* __restrict__ Wq, const float* __restrict__ Wk,
    const float* __restrict__ Wv,
    const float* __restrict__ Wout, const float* __restrict__ W1,
    const float* __restrict__ W2,
    float* __restrict__ q,
    unsigned short* __restrict__ kb, unsigned short* __restrict__ vb,
    unsigned short* __restrict__ WoutP, unsigned short* __restrict__ W1P,
    unsigned short* __restrict__ W2P)
{
    __shared__ __align__(16) unsigned short hB[16][128];  // 4 KB swizzled bf16
    const int t = threadIdx.x;
    const int bid = blockIdx.x;
    const int row0 = bid * 16;

    if (t < 64)       pack_unit(bid * 2,     t,       Wout, W1, W2, WoutP, W1P, W2P);
    else if (t < 128) pack_unit(bid * 2 + 1, t - 64,  Wout, W1, W2, WoutP, W1P, W2P);
    else if (t < 192 && bid < 32)
                      pack_unit(256 + bid,   t - 128, Wout, W1, W2, WoutP, W1P, W2P);

    {
        const int r = t >> 5, l = t & 31;
        const float4 xv = reinterpret_cast<const float4*>(
            x + (size_t)(row0 + r) * C_DIM)[l];
        float s  = xv.x + xv.y + xv.z + xv.w;
        float ss = xv.x*xv.x + xv.y*xv.y + xv.z*xv.z + xv.w*xv.w;
        #pragma unroll
        for (int m = 16; m >= 1; m >>= 1) {
            s  += __shfl_xor(s,  m);
            ss += __shfl_xor(ss, m);
        }
        const float mu  = s * (1.0f / 128.0f);
        const float var = ss * (1.0f / 128.0f) - mu * mu;
        const float inv = rsqrtf(var + LN_EPS);
        union { unsigned long long u64; unsigned short u16[4]; } pk;
        pk.u16[0] = f2bf((xv.x - mu) * inv);
        pk.u16[1] = f2bf((xv.y - mu) * inv);
        pk.u16[2] = f2bf((xv.z - mu) * inv);
        pk.u16[3] = f2bf((xv.w - mu) * inv);
        *reinterpret_cast<unsigned long long*>(
            reinterpret_cast<char*>(&hB[0][0]) +
            r * 256 + ((l * 8) ^ ((r & 7) << 4))) = pk.u64;
    }
    __syncthreads();

    {
        const int wv = t >> 6, lane = t & 63;
        s16x8 afr[4];
        #pragma unroll
        for (int ks = 0; ks < 4; ++ks) afr[ks] = lda_frag(&hB[0][0], 256, ks, lane);

        const int n = wv * 16 + (lane & 15);
        #pragma unroll
        for (int p = 0; p < 3; ++p) {
            const float* W = (p == 0) ? Wq : (p == 1) ? Wk : Wv;
            f32x4 acc = {0.f, 0.f, 0.f, 0.f};
            #pragma unroll
            for (int ks = 0; ks < 4; ++ks) {
                const int k0 = ks * 32 + ((lane >> 4) << 3);
                const float4* src = reinterpret_cast<const float4*>(
                    W + (size_t)n * C_DIM + k0);
                const float4 a = src[0], b = src[1];
                s16x8 bfr;
                bfr[0] = (short)f2bf(a.x); bfr[1] = (short)f2bf(a.y);
                bfr[2] = (short)f2bf(a.z); bfr[3] = (short)f2bf(a.w);
                bfr[4] = (short)f2bf(b.x); bfr[5] = (short)f2bf(b.y);
                bfr[6] = (short)f2bf(b.z); bfr[7] = (short)f2bf(b.w);
                acc = __builtin_amdgcn_mfma_f32_16x16x32_bf16(afr[ks], bfr, acc, 0, 0, 0);
            }
            #pragma unroll
            for (int ii = 0; ii < 4; ++ii) {
                const int m = ((lane >> 4) << 2) + ii;   // 0..15
                const size_t off = (size_t)(row0 + m) * C_DIM + n;
                if (p == 0)      q[off]  = acc[ii];
                else if (p == 1) kb[off] = f2bf(acc[ii]);
                else             vb[off] = f2bf(acc[ii]);
            }
        }
    }
}

// ---------------------------------------------------------------------------
// K2a: attention only. 1 query row per block, 128 threads, grid 2048.
// Tiny LDS (3.2 KB) + 2-wave barriers => many blocks/CU, gathers overlap.
// ---------------------------------------------------------------------------
__global__ __launch_bounds__(128) void attn_kernel(
    const float* __restrict__ q, const unsigned short* __restrict__ kb,
    const unsigned short* __restrict__ vb, const float* __restrict__ pair,
    const int*  __restrict__ bidx, const float* __restrict__ Wb,
    unsigned short* __restrict__ ao)
{
    __shared__ __align__(16) float qS[128];
    __shared__ __align__(16) int   idxS[128];
    __shared__ __align__(16) float S[4][128];

    const int t   = threadIdx.x;
    const int row = blockIdx.x;

    const int j = bidx[(size_t)row * BLK_K + t];
    idxS[t] = j;
    qS[t] = q[(size_t)row * C_DIM + t];

    const f32x4* pr = reinterpret_cast<const f32x4*>(
        pair + ((size_t)row * N_ATOMS + (size_t)j) * C_PAIR);
    const f32x4 p0 = __builtin_nontemporal_load(pr + 0);
    const f32x4 p1 = __builtin_nontemporal_load(pr + 1);
    const f32x4 p2 = __builtin_nontemporal_load(pr + 2);
    const f32x4 p3 = __builtin_nontemporal_load(pr + 3);
    __syncthreads();

    // --- scores: thread t = key slot; bf16 k row gather ---
    {
        const uint4* kr = reinterpret_cast<const uint4*>(kb + (size_t)j * C_DIM);
        const float4* q4 = reinterpret_cast<const float4*>(qS);
        float sc[4];
        #pragma unroll
        for (int h = 0; h < 4; ++h) {
            float a = 0.f;
            #pragma unroll
            for (int d = 0; d < 4; ++d) {
                const uint4  kk = kr[h * 4 + d];
                const float4 qa = q4[h * 8 + d * 2];
                const float4 qc = q4[h * 8 + d * 2 + 1];
                a += bf_lo(kk.x)*qa.x + bf_hi(kk.x)*qa.y
                   + bf_lo(kk.y)*qa.z + bf_hi(kk.y)*qa.w;
                a += bf_lo(kk.z)*qc.x + bf_hi(kk.z)*qc.y
                   + bf_lo(kk.w)*qc.z + bf_hi(kk.w)*qc.w;
            }
            sc[h] = a;
        }
        const float pm = (p0.x+p0.y+p0.z+p0.w + p1.x+p1.y+p1.z+p1.w +
                          p2.x+p2.y+p2.z+p2.w + p3.x+p3.y+p3.z+p3.w) * (1.0f/16.0f);
        const float scale = 0.17677669529663687f;  // 1/sqrt(32)
        #pragma unroll
        for (int h = 0; h < 4; ++h)
            S[h][t] = sc[h] * scale + pm * Wb[h];
    }
    __syncthreads();

    // --- softmax per head (32-lane group per head) ---
    {
        const int g = t >> 5, l = t & 31;
        const float v0 = S[g][l], v1 = S[g][l + 32],
                    v2 = S[g][l + 64], v3 = S[g][l + 96];
        float mx = fmaxf(fmaxf(v0, v1), fmaxf(v2, v3));
        #pragma unroll
        for (int m = 16; m >= 1; m >>= 1) mx = fmaxf(mx, __shfl_xor(mx, m));
        const float e0 = __expf(v0 - mx), e1 = __expf(v1 - mx),
                    e2 = __expf(v2 - mx), e3 = __expf(v3 - mx);
        float sm = e0 + e1 + e2 + e3;
        #pragma unroll
        for (int m = 16; m >= 1; m >>= 1) sm += __shfl_xor(sm, m);
        const float rs = 1.0f / sm;
        S[g][l]      = e0 * rs;
        S[g][l + 32] = e1 * rs;
        S[g][l + 64] = e2 * rs;
        S[g][l + 96] = e3 * rs;
    }
    __syncthreads();

    // --- PV: thread t = output dim; coalesced bf16 v reads; bf16 ao out ---
    {
        const int hh = t >> 5;
        const float4* Sv = reinterpret_cast<const float4*>(&S[hh][0]);
        const int4*   iv = reinterpret_cast<const int4*>(idxS);
        float acc = 0.f;
        #pragma unroll 8
        for (int bq = 0; bq < 32; ++bq) {
            const float4 s4 = Sv[bq];
            const int4   j4 = iv[bq];
            acc += s4.x * bf2f(vb[(size_t)j4.x * C_DIM + t]);
            acc += s4.y * bf2f(vb[(size_t)j4.y * C_DIM + t]);
            acc += s4.z * bf2f(vb[(size_t)j4.z * C_DIM + t]);
            acc += s4.w * bf2f(vb[(size_t)j4.w * C_DIM + t]);
        }
        ao[(size_t)row * C_DIM + t] = f2bf(acc);
    }
}

// ---------------------------------------------------------------------------
// K2b: x1 = x + ao@Wout.T ; h2 = LN(x1) ; out = x1 + silu(h2@W1.T+b1)@W2.T+b2
// 512 threads (8 waves), 16 rows/block, grid 128. Full M=16 MFMA tiles.
// ---------------------------------------------------------------------------
__global__ __launch_bounds__(512) void mlp_kernel(
    const unsigned short* __restrict__ ao, const float* __restrict__ x,
    const unsigned short* __restrict__ WoutP,
    const unsigned short* __restrict__ W1P, const float* __restrict__ b1,
    const unsigned short* __restrict__ W2P, const float* __restrict__ b2,
    float* __restrict__ out)
{
    __shared__ __align__(16) unsigned short aoB[16][128]; // 4 KB swz
    __shared__ __align__(16) float ys[16][128];           // 8 KB x1
    __shared__ __align__(16) unsigned short h2B[16][128]; // 4 KB swz
    __shared__ __align__(16) unsigned short gsB[16][512]; // 16 KB swz

    const int t = threadIdx.x;
    const int row0 = blockIdx.x * 16;
    const int wv = t >> 6, lane = t & 63;

    // --- stage ao (swizzled bf16) and x (f32) ---
    {
        const int m = t >> 5, g = t & 31;   // 16 rows x 32 8B-chunks
        const unsigned long long v = *reinterpret_cast<const unsigned long long*>(
            ao + (size_t)(row0 + m) * C_DIM + g * 4);
        *reinterpret_cast<unsigned long long*>(
            reinterpret_cast<char*>(&aoB[0][0]) +
            m * 256 + ((g * 8) ^ ((m & 7) << 4))) = v;
        const float4 xv = reinterpret_cast<const float4*>(
            x + (size_t)(row0 + m) * C_DIM)[g];
        *reinterpret_cast<float4*>(&ys[m][g * 4]) = xv;
    }
    __syncthreads();

    // --- P: x1 = x + ao @ Wout.T (8 waves, wave w -> col tile w) ---
    {
        f32x4 acc = {0.f, 0.f, 0.f, 0.f};
        const s16x8* Bp = reinterpret_cast<const s16x8*>(WoutP);
        #pragma unroll
        for (int ks = 0; ks < 4; ++ks) {
            const s16x8 a = lda_frag(&aoB[0][0], 256, ks, lane);
            const s16x8 b = Bp[(wv * 4 + ks) * 64 + lane];
            acc = __builtin_amdgcn_mfma_f32_16x16x32_bf16(a, b, acc, 0, 0, 0);
        }
        const int c = wv * 16 + (lane & 15);
        #pragma unroll
        for (int i = 0; i < 4; ++i) {
            const int m = ((lane >> 4) << 2) + i;   // 0..15
            ys[m][c] += acc[i];
        }
    }
    __syncthreads();

    // --- LN: h2 = LayerNorm(x1) -> swizzled bf16 ---
    {
        const int rr = t >> 5, l = t & 31;
        const float4 yv = *reinterpret_cast<const float4*>(&ys[rr][l * 4]);
        float s  = yv.x + yv.y + yv.z + yv.w;
        float ss = yv.x*yv.x + yv.y*yv.y + yv.z*yv.z + yv.w*yv.w;
        #pragma unroll
        for (int m = 16; m >= 1; m >>= 1) {
            s  += __shfl_xor(s,  m);
            ss += __shfl_xor(ss, m);
        }
        const float mu  = s * (1.0f / 128.0f);
        const float var = ss * (1.0f / 128.0f) - mu * mu;
        const float inv = rsqrtf(var + LN_EPS);
        union { unsigned long long u64; unsigned short u16[4]; } pk;
        pk.u16[0] = f2bf((yv.x - mu) * inv);
        pk.u16[1] = f2bf((yv.y - mu) * inv);
        pk.u16[2] = f2bf((yv.z - mu) * inv);
        pk.u16[3] = f2bf((yv.w - mu) * inv);
        *reinterpret_cast<unsigned long long*>(
            reinterpret_cast<char*>(&h2B[0][0]) +
            rr * 256 + ((l * 8) ^ ((rr & 7) << 4))) = pk.u64;
    }
    __syncthreads();

    // --- M1: gs = silu(h2 @ W1.T + b1)  (8 waves x 4 col tiles) ---
    {
        s16x8 afr[4];
        #pragma unroll
        for (int ks = 0; ks < 4; ++ks) afr[ks] = lda_frag(&h2B[0][0], 256, ks, lane);
        const s16x8* Bp = reinterpret_cast<const s16x8*>(W1P);
        #pragma unroll
        for (int tt = 0; tt < 4; ++tt) {
            const int tile = wv * 4 + tt;
            f32x4 acc = {0.f, 0.f, 0.f, 0.f};
            #pragma unroll
            for (int ks = 0; ks < 4; ++ks) {
                const s16x8 b = Bp[(tile * 4 + ks) * 64 + lane];
                acc = __builtin_amdgcn_mfma_f32_16x16x32_bf16(afr[ks], b, acc, 0, 0, 0);
            }
            const int c = tile * 16 + (lane & 15);
            const float bb = b1[c];
            #pragma unroll
            for (int i = 0; i < 4; ++i) {
                const int m = ((lane >> 4) << 2) + i;  // 0..15
                const float g = acc[i] + bb;
                const float sv = g / (1.0f + __expf(-g));
                *reinterpret_cast<unsigned short*>(
                    reinterpret_cast<char*>(&gsB[0][0]) +
                    m * 1024 + ((c * 2) ^ ((m & 7) << 4))) = f2bf(sv);
            }
        }
    }
    __syncthreads();

    // --- M2: out = x1 + gs @ W2.T + b2  (8 waves, K=512) ---
    {
        f32x4 acc = {0.f, 0.f, 0.f, 0.f};
        const s16x8* Bp = reinterpret_cast<const s16x8*>(W2P);
        #pragma unroll
        for (int ks = 0; ks < 16; ++ks) {
            const s16x8 a = lda_frag(&gsB[0][0], 1024, ks, lane);
            const s16x8 b = Bp[(wv * 16 + ks) * 64 + lane];
            acc = __builtin_amdgcn_mfma_f32_16x16x32_bf16(a, b, acc, 0, 0, 0);
        }
        const int c = wv * 16 + (lane & 15);
        const float bb = b2[c];
        #pragma unroll
        for (int i = 0; i < 4; ++i) {
            const int m = ((lane >> 4) << 2) + i;   // 0..15
            out[(size_t)(row0 + m) * C_DIM + c] = ys[m][c] + bb + acc[i];
        }
    }
}

// ---------------------------------------------------------------------------
extern "C" void kernel_launch(void* const* d_in, const int* in_sizes, int n_in,
                              void* d_out, int out_size, void* d_ws, size_t ws_size,
                              hipStream_t stream)
{
    const float* x    = (const float*)d_in[0];
    const float* pair = (const float*)d_in[1];
    const int*   bidx = (const int*)  d_in[2];
    const float* Wq   = (const float*)d_in[3];
    const float* Wk   = (const float*)d_in[4];
    const float* Wv   = (const float*)d_in[5];
    const float* Wb   = (const float*)d_in[6];
    const float* Wout = (const float*)d_in[7];
    const float* W1   = (const float*)d_in[8];
    const float* b1   = (const float*)d_in[9];
    const float* W2   = (const float*)d_in[10];
    const float* b2   = (const float*)d_in[11];
    float* out = (float*)d_out;

    char* ws = (char*)d_ws;
    float*          q     = (float*)ws;                               // 1 MB
    unsigned short* kb    = (unsigned short*)(ws + (1 << 20));        // 0.5 MB
    unsigned short* vb    = (unsigned short*)(ws + (1 << 20) + (1 << 19));
    unsigned short* ao    = (unsigned short*)(ws + (2 << 20));        // 0.5 MB
    unsigned short* WoutP = (unsigned short*)(ws + (2 << 20) + (1 << 19));
    unsigned short* W1P   = (unsigned short*)(ws + (2 << 20) + (1 << 19) + (32 << 10));
    unsigned short* W2P   = (unsigned short*)(ws + (2 << 20) + (1 << 19) + (160 << 10));

    hipLaunchKernelGGL(ln_qkv_kernel, dim3(N_ATOMS / 16), dim3(512), 0, stream,
                       x, Wq, Wk, Wv, Wout, W1, W2, q, kb, vb, WoutP, W1P, W2P);
    hipLaunchKernelGGL(attn_kernel, dim3(N_ATOMS), dim3(128), 0, stream,
                       q, kb, vb, pair, bidx, Wb, ao);
    hipLaunchKernelGGL(mlp_kernel, dim3(N_ATOMS / 16), dim3(512), 0, stream,
                       ao, x, WoutP, W1P, b1, W2P, b2, out);
}

// Round 9
// 44.876 us; speedup vs baseline: 1.0593x; 1.0593x over previous
//
#include <hip/hip_runtime.h>
#include <hip/hip_bf16.h>

#define N_ATOMS 2048
#define C_DIM   128
#define C_PAIR  16
#define BLK_K   128
#define LN_EPS  1e-5f

typedef float f32x4 __attribute__((ext_vector_type(4)));
typedef short s16x8 __attribute__((ext_vector_type(8)));

__device__ __forceinline__ float bf_lo(unsigned int p) {
    union { unsigned int i; float f; } u; u.i = p << 16; return u.f;
}
__device__ __forceinline__ float bf_hi(unsigned int p) {
    union { unsigned int i; float f; } u; u.i = p & 0xffff0000u; return u.f;
}
__device__ __forceinline__ unsigned short f2bf(float f) {
    union { float f; unsigned int i; } u; u.f = f;
    const unsigned int r = u.i + 0x7fffu + ((u.i >> 16) & 1u);  // RNE
    return (unsigned short)(r >> 16);
}

// A-fragment read from swizzled bf16 LDS tile [16][rowBytes/2].
__device__ __forceinline__ s16x8 lda_frag(const unsigned short* base,
                                          int rowBytes, int kstep, int lane) {
    const int m    = lane & 15;
    const int koff = kstep * 64 + ((lane >> 4) << 4);
    const int addr = m * rowBytes + (koff ^ ((m & 7) << 4));
    return *reinterpret_cast<const s16x8*>(
        reinterpret_cast<const char*>(base) + addr);
}

// ---------------------------------------------------------------------------
// Weight packing: W [Nout][K] f32 row-major -> bf16 B-fragment stream.
// units: Wout 32 (8x4), W1 128 (32x4), W2 128 (8x16)  => 288 total
// ---------------------------------------------------------------------------
__device__ void pack_unit(int u, int lane,
                          const float* __restrict__ Wout,
                          const float* __restrict__ W1,
                          const float* __restrict__ W2,
                          unsigned short* __restrict__ WoutP,
                          unsigned short* __restrict__ W1P,
                          unsigned short* __restrict__ W2P)
{
    const float* W; unsigned short* P; int K, local;
    if (u < 32)       { W = Wout; P = WoutP; K = 128; local = u; }
    else if (u < 160) { W = W1;   P = W1P;   K = 128; local = u - 32; }
    else              { W = W2;   P = W2P;   K = 512; local = u - 160; }
    const int ksteps = K >> 5;
    const int ntile  = local / ksteps;
    const int kstep  = local - ntile * ksteps;
    const int n  = ntile * 16 + (lane & 15);
    const int k0 = kstep * 32 + ((lane >> 4) << 3);
    const float4* src = reinterpret_cast<const float4*>(W + (size_t)n * K + k0);
    const float4 a = src[0], b = src[1];
    s16x8 o;
    o[0] = (short)f2bf(a.x); o[1] = (short)f2bf(a.y);
    o[2] = (short)f2bf(a.z); o[3] = (short)f2bf(a.w);
    o[4] = (short)f2bf(b.x); o[5] = (short)f2bf(b.y);
    o[6] = (short)f2bf(b.z); o[7] = (short)f2bf(b.w);
    reinterpret_cast<s16x8*>(P)[local * 64 + lane] = o;
}

// ---------------------------------------------------------------------------
// K1: LayerNorm(x) -> swizzled bf16 LDS; q/k/v via MFMA, weight B-fragments
// loaded directly from f32 global. 512 threads, 16 rows/block, grid 128.
// (unchanged from R5/R6 best config)
// ---------------------------------------------------------------------------
__global__ __launch_bounds__(512) void ln_qkv_kernel(
    const float* __restrict__ x,
    const float* __restrict__ Wq, const float* __restrict__ Wk,
    const float* __restrict__ Wv,
    const float* __restrict__ Wout, const float* __restrict__ W1,
    const float* __restrict__ W2,
    float* __restrict__ q,
    unsigned short* __restrict__ kb, unsigned short* __restrict__ vb,
    unsigned short* __restrict__ WoutP, unsigned short* __restrict__ W1P,
    unsigned short* __restrict__ W2P)
{
    __shared__ __align__(16) unsigned short hB[16][128];  // 4 KB swizzled bf16
    const int t = threadIdx.x;
    const int bid = blockIdx.x;
    const int row0 = bid * 16;

    if (t < 64)       pack_unit(bid * 2,     t,       Wout, W1, W2, WoutP, W1P, W2P);
    else if (t < 128) pack_unit(bid * 2 + 1, t - 64,  Wout, W1, W2, WoutP, W1P, W2P);
    else if (t < 192 && bid < 32)
                      pack_unit(256 + bid,   t - 128, Wout, W1, W2, WoutP, W1P, W2P);

    {
        const int r = t >> 5, l = t & 31;
        const float4 xv = reinterpret_cast<const float4*>(
            x + (size_t)(row0 + r) * C_DIM)[l];
        float s  = xv.x + xv.y + xv.z + xv.w;
        float ss = xv.x*xv.x + xv.y*xv.y + xv.z*xv.z + xv.w*xv.w;
        #pragma unroll
        for (int m = 16; m >= 1; m >>= 1) {
            s  += __shfl_xor(s,  m);
            ss += __shfl_xor(ss, m);
        }
        const float mu  = s * (1.0f / 128.0f);
        const float var = ss * (1.0f / 128.0f) - mu * mu;
        const float inv = rsqrtf(var + LN_EPS);
        union { unsigned long long u64; unsigned short u16[4]; } pk;
        pk.u16[0] = f2bf((xv.x - mu) * inv);
        pk.u16[1] = f2bf((xv.y - mu) * inv);
        pk.u16[2] = f2bf((xv.z - mu) * inv);
        pk.u16[3] = f2bf((xv.w - mu) * inv);
        *reinterpret_cast<unsigned long long*>(
            reinterpret_cast<char*>(&hB[0][0]) +
            r * 256 + ((l * 8) ^ ((r & 7) << 4))) = pk.u64;
    }
    __syncthreads();

    {
        const int wv = t >> 6, lane = t & 63;
        s16x8 afr[4];
        #pragma unroll
        for (int ks = 0; ks < 4; ++ks) afr[ks] = lda_frag(&hB[0][0], 256, ks, lane);

        const int n = wv * 16 + (lane & 15);
        #pragma unroll
        for (int p = 0; p < 3; ++p) {
            const float* W = (p == 0) ? Wq : (p == 1) ? Wk : Wv;
            f32x4 acc = {0.f, 0.f, 0.f, 0.f};
            #pragma unroll
            for (int ks = 0; ks < 4; ++ks) {
                const int k0 = ks * 32 + ((lane >> 4) << 3);
                const float4* src = reinterpret_cast<const float4*>(
                    W + (size_t)n * C_DIM + k0);
                const float4 a = src[0], b = src[1];
                s16x8 bfr;
                bfr[0] = (short)f2bf(a.x); bfr[1] = (short)f2bf(a.y);
                bfr[2] = (short)f2bf(a.z); bfr[3] = (short)f2bf(a.w);
                bfr[4] = (short)f2bf(b.x); bfr[5] = (short)f2bf(b.y);
                bfr[6] = (short)f2bf(b.z); bfr[7] = (short)f2bf(b.w);
                acc = __builtin_amdgcn_mfma_f32_16x16x32_bf16(afr[ks], bfr, acc, 0, 0, 0);
            }
            #pragma unroll
            for (int ii = 0; ii < 4; ++ii) {
                const int m = ((lane >> 4) << 2) + ii;   // 0..15
                const size_t off = (size_t)(row0 + m) * C_DIM + n;
                if (p == 0)      q[off]  = acc[ii];
                else if (p == 1) kb[off] = f2bf(acc[ii]);
                else             vb[off] = f2bf(acc[ii]);
            }
        }
    }
}

// ---------------------------------------------------------------------------
// K2: wave-per-row BARRIER-FREE attention + one barrier + MFMA MLP.
// 512 threads (8 waves), 8 query rows/block, grid 256. Wave w owns row w:
// lane l covers key slots {l, l+64}; softmax via 64-wide shfl; P/idx through
// wave-private LDS (no __syncthreads until the MLP tile is assembled).
// ---------------------------------------------------------------------------
__global__ __launch_bounds__(512, 4) void attn_mlp_kernel(
    const float* __restrict__ q, const unsigned short* __restrict__ kb,
    const unsigned short* __restrict__ vb, const float* __restrict__ pair,
    const int*  __restrict__ bidx, const float* __restrict__ Wb,
    const float* __restrict__ x,
    const unsigned short* __restrict__ WoutP,
    const unsigned short* __restrict__ W1P, const float* __restrict__ b1,
    const unsigned short* __restrict__ W2P, const float* __restrict__ b2,
    float* __restrict__ out)
{
    __shared__ __align__(16) float qS[8][128];            // 4 KB (wave-private)
    __shared__ __align__(16) int   idxS[8][128];          // 4 KB (wave-private)
    __shared__ __align__(16) float Sl[8][4][128];         // 16 KB (wave-private)
    __shared__ __align__(16) float ys[8][128];            // 4 KB x1
    __shared__ __align__(16) unsigned short aoB[16][128]; // 4 KB swz
    __shared__ __align__(16) unsigned short h2B[16][128]; // 4 KB swz
    __shared__ __align__(16) unsigned short gsB[16][512]; // 16 KB swz

    const int t = threadIdx.x;
    const int row0 = blockIdx.x * 8;
    const int w = t >> 6, lane = t & 63;
    const int row = row0 + w;

    // --- pads (MFMA rows 8..15) + x staging; all barrier-free ---
    {
        const uint4 z = {0,0,0,0};
        if (t < 128)      reinterpret_cast<uint4*>(&aoB[8][0])[t] = z;
        else if (t < 256) reinterpret_cast<uint4*>(&h2B[8][0])[t - 128] = z;
        reinterpret_cast<uint4*>(&gsB[8][0])[t] = z;           // 512 x 16B
        if (t < 256) {
            const int r2 = t >> 5, l2 = t & 31;
            const float4 xv = reinterpret_cast<const float4*>(
                x + (size_t)(row0 + r2) * C_DIM)[l2];
            *reinterpret_cast<float4*>(&ys[r2][l2 * 4]) = xv;
        }
    }

    // ================= wave-local attention (NO barriers) =================
    const int j0 = bidx[(size_t)row * BLK_K + lane];
    const int j1 = bidx[(size_t)row * BLK_K + 64 + lane];
    idxS[w][lane] = j0;
    idxS[w][64 + lane] = j1;
    {
        const float2 q2 = *reinterpret_cast<const float2*>(
            q + (size_t)row * C_DIM + 2 * lane);
        *reinterpret_cast<float2*>(&qS[w][2 * lane]) = q2;
    }

    // pair gather: two 64B chunks (HBM, nontemporal)
    const f32x4* pr0 = reinterpret_cast<const f32x4*>(
        pair + ((size_t)row * N_ATOMS + (size_t)j0) * C_PAIR);
    const f32x4* pr1 = reinterpret_cast<const f32x4*>(
        pair + ((size_t)row * N_ATOMS + (size_t)j1) * C_PAIR);
    const f32x4 pa0 = __builtin_nontemporal_load(pr0 + 0);
    const f32x4 pa1 = __builtin_nontemporal_load(pr0 + 1);
    const f32x4 pa2 = __builtin_nontemporal_load(pr0 + 2);
    const f32x4 pa3 = __builtin_nontemporal_load(pr0 + 3);
    const f32x4 pb0 = __builtin_nontemporal_load(pr1 + 0);
    const f32x4 pb1 = __builtin_nontemporal_load(pr1 + 1);
    const f32x4 pb2 = __builtin_nontemporal_load(pr1 + 2);
    const f32x4 pb3 = __builtin_nontemporal_load(pr1 + 3);

    // QK: both key rows, q chunks re-read from wave-private LDS
    float sc0[4], sc1[4];
    {
        const uint4* kr0 = reinterpret_cast<const uint4*>(kb + (size_t)j0 * C_DIM);
        const uint4* kr1 = reinterpret_cast<const uint4*>(kb + (size_t)j1 * C_DIM);
        #pragma unroll
        for (int h = 0; h < 4; ++h) {
            float a0 = 0.f, a1 = 0.f;
            #pragma unroll
            for (int c = 0; c < 4; ++c) {
                const uint4 k0 = kr0[h * 4 + c];
                const uint4 k1 = kr1[h * 4 + c];
                const float4 qa = *reinterpret_cast<const float4*>(
                    &qS[w][h * 32 + c * 8]);
                const float4 qc = *reinterpret_cast<const float4*>(
                    &qS[w][h * 32 + c * 8 + 4]);
                a0 += bf_lo(k0.x)*qa.x + bf_hi(k0.x)*qa.y
                    + bf_lo(k0.y)*qa.z + bf_hi(k0.y)*qa.w
                    + bf_lo(k0.z)*qc.x + bf_hi(k0.z)*qc.y
                    + bf_lo(k0.w)*qc.z + bf_hi(k0.w)*qc.w;
                a1 += bf_lo(k1.x)*qa.x + bf_hi(k1.x)*qa.y
                    + bf_lo(k1.y)*qa.z + bf_hi(k1.y)*qa.w
                    + bf_lo(k1.z)*qc.x + bf_hi(k1.z)*qc.y
                    + bf_lo(k1.w)*qc.z + bf_hi(k1.w)*qc.w;
            }
            sc0[h] = a0; sc1[h] = a1;
        }
    }

    const float pm0 = (pa0.x+pa0.y+pa0.z+pa0.w + pa1.x+pa1.y+pa1.z+pa1.w +
                       pa2.x+pa2.y+pa2.z+pa2.w + pa3.x+pa3.y+pa3.z+pa3.w) * (1.0f/16.0f);
    const float pm1 = (pb0.x+pb0.y+pb0.z+pb0.w + pb1.x+pb1.y+pb1.z+pb1.w +
                       pb2.x+pb2.y+pb2.z+pb2.w + pb3.x+pb3.y+pb3.z+pb3.w) * (1.0f/16.0f);
    const float scale = 0.17677669529663687f;  // 1/sqrt(32)

    // softmax per head over 128 slots (64-wide shuffles), P -> wave-private LDS
    #pragma unroll
    for (int h = 0; h < 4; ++h) {
        const float wb = Wb[h];
        const float s0 = sc0[h] * scale + pm0 * wb;
        const float s1 = sc1[h] * scale + pm1 * wb;
        float mx = fmaxf(s0, s1);
        #pragma unroll
        for (int m = 32; m >= 1; m >>= 1) mx = fmaxf(mx, __shfl_xor(mx, m));
        const float e0 = __expf(s0 - mx), e1 = __expf(s1 - mx);
        float sm = e0 + e1;
        #pragma unroll
        for (int m = 32; m >= 1; m >>= 1) sm += __shfl_xor(sm, m);
        const float rs = 1.0f / sm;
        Sl[w][h][lane]      = e0 * rs;
        Sl[w][h][lane + 64] = e1 * rs;
    }

    // PV: lane owns adjacent dims d0=2*lane, d0+1 (4B v loads, same head)
    {
        const int d0 = 2 * lane;
        const int hh = lane >> 4;          // d0>>5
        float acc0 = 0.f, acc1 = 0.f;
        #pragma unroll 8
        for (int k4 = 0; k4 < 32; ++k4) {
            const int4   j4 = *reinterpret_cast<const int4*>(&idxS[w][k4 * 4]);
            const float4 p4 = *reinterpret_cast<const float4*>(&Sl[w][hh][k4 * 4]);
            unsigned int v01;
            v01 = *reinterpret_cast<const unsigned int*>(vb + (size_t)j4.x * C_DIM + d0);
            acc0 += p4.x * bf_lo(v01); acc1 += p4.x * bf_hi(v01);
            v01 = *reinterpret_cast<const unsigned int*>(vb + (size_t)j4.y * C_DIM + d0);
            acc0 += p4.y * bf_lo(v01); acc1 += p4.y * bf_hi(v01);
            v01 = *reinterpret_cast<const unsigned int*>(vb + (size_t)j4.z * C_DIM + d0);
            acc0 += p4.z * bf_lo(v01); acc1 += p4.z * bf_hi(v01);
            v01 = *reinterpret_cast<const unsigned int*>(vb + (size_t)j4.w * C_DIM + d0);
            acc0 += p4.w * bf_lo(v01); acc1 += p4.w * bf_hi(v01);
        }
        // write two adjacent bf16 into swizzled aoB row w
        const unsigned int pk = (unsigned int)f2bf(acc0) |
                                ((unsigned int)f2bf(acc1) << 16);
        *reinterpret_cast<unsigned int*>(
            reinterpret_cast<char*>(&aoB[0][0]) +
            w * 256 + ((4 * lane) ^ ((w & 7) << 4))) = pk;
    }

    __syncthreads();   // the ONLY barrier between attention and MLP

    // ================= MLP: P -> LN -> M1 -> M2 =================
    {
        f32x4 acc = {0.f, 0.f, 0.f, 0.f};
        const s16x8* Bp = reinterpret_cast<const s16x8*>(WoutP);
        #pragma unroll
        for (int ks = 0; ks < 4; ++ks) {
            const s16x8 a = lda_frag(&aoB[0][0], 256, ks, lane);
            const s16x8 b = Bp[(w * 4 + ks) * 64 + lane];
            acc = __builtin_amdgcn_mfma_f32_16x16x32_bf16(a, b, acc, 0, 0, 0);
        }
        const int c = w * 16 + (lane & 15);
        #pragma unroll
        for (int i = 0; i < 4; ++i) {
            const int m = ((lane >> 4) << 2) + i;   // 0..15
            if (m < 8) ys[m][c] += acc[i];
        }
    }
    __syncthreads();

    if (t < 256) {
        const int rr = t >> 5, l = t & 31;
        const float4 yv = *reinterpret_cast<const float4*>(&ys[rr][l * 4]);
        float s  = yv.x + yv.y + yv.z + yv.w;
        float ss = yv.x*yv.x + yv.y*yv.y + yv.z*yv.z + yv.w*yv.w;
        #pragma unroll
        for (int m = 16; m >= 1; m >>= 1) {
            s  += __shfl_xor(s,  m);
            ss += __shfl_xor(ss, m);
        }
        const float mu  = s * (1.0f / 128.0f);
        const float var = ss * (1.0f / 128.0f) - mu * mu;
        const float inv = rsqrtf(var + LN_EPS);
        union { unsigned long long u64; unsigned short u16[4]; } pk;
        pk.u16[0] = f2bf((yv.x - mu) * inv);
        pk.u16[1] = f2bf((yv.y - mu) * inv);
        pk.u16[2] = f2bf((yv.z - mu) * inv);
        pk.u16[3] = f2bf((yv.w - mu) * inv);
        *reinterpret_cast<unsigned long long*>(
            reinterpret_cast<char*>(&h2B[0][0]) +
            rr * 256 + ((l * 8) ^ ((rr & 7) << 4))) = pk.u64;
    }
    __syncthreads();

    {
        s16x8 afr[4];
        #pragma unroll
        for (int ks = 0; ks < 4; ++ks) afr[ks] = lda_frag(&h2B[0][0], 256, ks, lane);
        const s16x8* Bp = reinterpret_cast<const s16x8*>(W1P);
        #pragma unroll
        for (int tt = 0; tt < 4; ++tt) {
            const int tile = w * 4 + tt;
            f32x4 acc = {0.f, 0.f, 0.f, 0.f};
            #pragma unroll
            for (int ks = 0; ks < 4; ++ks) {
                const s16x8 b = Bp[(tile * 4 + ks) * 64 + lane];
                acc = __builtin_amdgcn_mfma_f32_16x16x32_bf16(afr[ks], b, acc, 0, 0, 0);
            }
            const int c = tile * 16 + (lane & 15);
            const float bb = b1[c];
            #pragma unroll
            for (int i = 0; i < 4; ++i) {
                const int m = ((lane >> 4) << 2) + i;  // 0..15
                if (m < 8) {
                    const float g = acc[i] + bb;
                    const float sv = g / (1.0f + __expf(-g));
                    *reinterpret_cast<unsigned short*>(
                        reinterpret_cast<char*>(&gsB[0][0]) +
                        m * 1024 + ((c * 2) ^ ((m & 7) << 4))) = f2bf(sv);
                }
            }
        }
    }
    __syncthreads();

    {
        f32x4 acc = {0.f, 0.f, 0.f, 0.f};
        const s16x8* Bp = reinterpret_cast<const s16x8*>(W2P);
        #pragma unroll
        for (int ks = 0; ks < 16; ++ks) {
            const s16x8 a = lda_frag(&gsB[0][0], 1024, ks, lane);
            const s16x8 b = Bp[(w * 16 + ks) * 64 + lane];
            acc = __builtin_amdgcn_mfma_f32_16x16x32_bf16(a, b, acc, 0, 0, 0);
        }
        const int c = w * 16 + (lane & 15);
        const float bb = b2[c];
        #pragma unroll
        for (int i = 0; i < 4; ++i) {
            const int m = ((lane >> 4) << 2) + i;   // 0..15
            if (m < 8)
                out[(size_t)(row0 + m) * C_DIM + c] = ys[m][c] + bb + acc[i];
        }
    }
}

// ---------------------------------------------------------------------------
extern "C" void kernel_launch(void* const* d_in, const int* in_sizes, int n_in,
                              void* d_out, int out_size, void* d_ws, size_t ws_size,
                              hipStream_t stream)
{
    const float* x    = (const float*)d_in[0];
    const float* pair = (const float*)d_in[1];
    const int*   bidx = (const int*)  d_in[2];
    const float* Wq   = (const float*)d_in[3];
    const float* Wk   = (const float*)d_in[4];
    const float* Wv   = (const float*)d_in[5];
    const float* Wb   = (const float*)d_in[6];
    const float* Wout = (const float*)d_in[7];
    const float* W1   = (const float*)d_in[8];
    const float* b1   = (const float*)d_in[9];
    const float* W2   = (const float*)d_in[10];
    const float* b2   = (const float*)d_in[11];
    float* out = (float*)d_out;

    char* ws = (char*)d_ws;
    float*          q     = (float*)ws;                               // 1 MB
    unsigned short* kb    = (unsigned short*)(ws + (1 << 20));        // 0.5 MB
    unsigned short* vb    = (unsigned short*)(ws + (1 << 20) + (1 << 19));
    unsigned short* WoutP = (unsigned short*)(ws + (2 << 20));        // 32 KB
    unsigned short* W1P   = (unsigned short*)(ws + (2 << 20) + (32 << 10));  // 128 KB
    unsigned short* W2P   = (unsigned short*)(ws + (2 << 20) + (160 << 10)); // 128 KB

    hipLaunchKernelGGL(ln_qkv_kernel, dim3(N_ATOMS / 16), dim3(512), 0, stream,
                       x, Wq, Wk, Wv, Wout, W1, W2, q, kb, vb, WoutP, W1P, W2P);
    hipLaunchKernelGGL(attn_mlp_kernel, dim3(N_ATOMS / 8), dim3(512), 0, stream,
                       q, kb, vb, pair, bidx, Wb, x, WoutP, W1P, b1, W2P, b2, out);
}